// Round 4
// baseline (1842.224 us; speedup 1.0000x reference)
//
#include <hip/hip_runtime.h>
#include <math.h>

// ---------------------------------------------------------------------------
// Model_Recursive_LSTM_v2 — round 3 resubmit (rounds 0-2: infra failures —
// GPUAcquisitionTimeout x2, container-failed x1; still no measurement).
// Correctness-first full-f32 implementation, unchanged and fully audited.
//
// Phases (all on `stream`):
//   1. comp-embedding MLP: 4x gemm_nt+ELU over 16384 rows (1024->600->350->200->180)
//   2. leaf LSTM  (cl): batch 1536 (6 leaves x 256), T=8
//   3. leaf concat block (no_nodes folded into bias)
//   4. mid LSTM   (nl): batch 768 (3 mids x 256), T=2
//   5. mid concat block (no_comps folded into bias)
//   6. root LSTM  (nl): batch 256, T=3
//   7. root concat + regression + pred dot
//
// LSTM trick: x@Wih^T for all timesteps precomputed as one GEMM (XW); each
// sequential step is G = h@Whh^T (GEMM) then a fused gate-update kernel.
// ---------------------------------------------------------------------------

#define BM 64
#define BN 64
#define BK 16

__device__ __forceinline__ float elu1(float x) { return x > 0.f ? x : expm1f(x); }
__device__ __forceinline__ float sigm(float x) { return 1.f / (1.f + expf(-x)); }

// C[m,n] = act( sum_k A[m,k] * W[n, woff+k] + bias[n] )
// A: M x lda row-major, W: N x ldw row-major (column slice at woff), C: M x N
__global__ __launch_bounds__(256)
void gemm_nt(const float* __restrict__ A, int lda,
             const float* __restrict__ W, int ldw, int woff,
             const float* __restrict__ bias,
             float* __restrict__ C, int M, int N, int K, int act)
{
    __shared__ float As[BK][BM + 4];
    __shared__ float Ws[BK][BN + 4];
    const int tid = threadIdx.x;
    const int bm = blockIdx.x * BM;
    const int bn = blockIdx.y * BN;
    const int lr = tid >> 2;          // 0..63 row within tile (loader)
    const int lk = (tid & 3) << 2;    // 0,4,8,12 k within tile (loader)
    const int r0 = (tid >> 4) << 2;   // 0..60 row group (compute)
    const int c0 = (tid & 15) << 2;   // 0..60 col group (compute)
    float acc[4][4] = {};

    for (int k0 = 0; k0 < K; k0 += BK) {
        const int arow = bm + lr;
        const int wrow = bn + lr;
#pragma unroll
        for (int u = 0; u < 4; ++u) {
            const int k = k0 + lk + u;
            As[lk + u][lr] = (arow < M && k < K) ? A[arow * lda + k] : 0.f;
            Ws[lk + u][lr] = (wrow < N && k < K) ? W[wrow * ldw + woff + k] : 0.f;
        }
        __syncthreads();
#pragma unroll
        for (int kk = 0; kk < BK; ++kk) {
            float a[4], b[4];
#pragma unroll
            for (int i = 0; i < 4; ++i) a[i] = As[kk][r0 + i];
#pragma unroll
            for (int j = 0; j < 4; ++j) b[j] = Ws[kk][c0 + j];
#pragma unroll
            for (int i = 0; i < 4; ++i)
#pragma unroll
                for (int j = 0; j < 4; ++j)
                    acc[i][j] = fmaf(a[i], b[j], acc[i][j]);
        }
        __syncthreads();
    }
#pragma unroll
    for (int i = 0; i < 4; ++i) {
        const int row = bm + r0 + i;
        if (row >= M) continue;
#pragma unroll
        for (int j = 0; j < 4; ++j) {
            const int col = bn + c0 + j;
            if (col >= N) continue;
            float v = acc[i][j];
            if (bias) v += bias[col];
            if (act) v = elu1(v);
            C[row * N + col] = v;
        }
    }
}

// torch gate order i,f,g,o at column offsets 0,180,360,540 of the 720-wide G.
__global__ void lstm_gate(float* __restrict__ h, float* __restrict__ c,
                          const float* __restrict__ G, const float* __restrict__ XW,
                          int rows, int T, int t)
{
    int idx = blockIdx.x * blockDim.x + threadIdx.x;
    if (idx >= rows * 180) return;
    int n = idx / 180, e = idx - n * 180;
    const float* g  = G  + n * 720;
    const float* xw = XW + (n * T + t) * 720;
    float gi = g[e]       + xw[e];
    float gf = g[e + 180] + xw[e + 180];
    float gg = g[e + 360] + xw[e + 360];
    float go = g[e + 540] + xw[e + 540];
    float cv = sigm(gf) * c[idx] + sigm(gi) * tanhf(gg);
    c[idx] = cv;
    h[idx] = sigm(go) * tanhf(cv);
}

// leaf inputs: row r = (j*256+b)*8 + t  <-  embed row b*64 + 8j + t
__global__ void gather_leaf(const float* __restrict__ embed, float* __restrict__ Xg)
{
    int idx = blockIdx.x * blockDim.x + threadIdx.x;
    if (idx >= 12288 * 180) return;
    int r = idx / 180, e = idx - r * 180;
    int t = r & 7, nb = r >> 3;
    int b = nb & 255, j = nb >> 8;
    Xg[idx] = embed[(b * 64 + 8 * j + t) * 180 + e];
}

// mid inputs: row r = (i*256+b)*2 + t  <-  leaf_state row (2i+t)*256 + b
__global__ void gather_mid(const float* __restrict__ ls, float* __restrict__ Xg)
{
    int idx = blockIdx.x * blockDim.x + threadIdx.x;
    if (idx >= 1536 * 180) return;
    int r = idx / 180, e = idx - r * 180;
    int t = r & 1, m = r >> 1;
    int b = m & 255, i = m >> 8;
    Xg[idx] = ls[((2 * i + t) * 256 + b) * 180 + e];
}

// root inputs: row r = b*3 + t  <-  mid_state row t*256 + b
__global__ void gather_root(const float* __restrict__ ms, float* __restrict__ Xg)
{
    int idx = blockIdx.x * blockDim.x + threadIdx.x;
    if (idx >= 768 * 180) return;
    int r = idx / 180, e = idx - r * 180;
    int b = r / 3, t = r - b * 3;
    Xg[idx] = ms[(t * 256 + b) * 180 + e];
}

// Fold LSTM bias pairs and the constant concat halves into biases.
__global__ void bias_prep(const float* __restrict__ cl_bih, const float* __restrict__ cl_bhh,
                          const float* __restrict__ nl_bih, const float* __restrict__ nl_bhh,
                          const float* __restrict__ cc_w0, const float* __restrict__ cc_b0,
                          const float* __restrict__ no_nodes, const float* __restrict__ no_comps,
                          float* __restrict__ clb, float* __restrict__ nlb,
                          float* __restrict__ b1, float* __restrict__ b2)
{
    int tid = blockIdx.x * blockDim.x + threadIdx.x;
    if (tid < 720) {
        clb[tid] = cl_bih[tid] + cl_bhh[tid];
    } else if (tid < 1440) {
        int o = tid - 720;
        nlb[o] = nl_bih[o] + nl_bhh[o];
    } else if (tid < 1640) {
        int o = tid - 1440;
        float s = cc_b0[o];
        for (int e = 0; e < 180; ++e) s = fmaf(no_nodes[e], cc_w0[o * 360 + e], s);
        b1[o] = s;   // leaf: nodes half is constant no_nodes (cols 0:180)
    } else if (tid < 1840) {
        int o = tid - 1640;
        float s = cc_b0[o];
        for (int e = 0; e < 180; ++e) s = fmaf(no_comps[e], cc_w0[o * 360 + 180 + e], s);
        b2[o] = s;   // interior: comps half is constant no_comps (cols 180:360)
    }
}

__global__ void pred_kernel(const float* __restrict__ x, const float* __restrict__ pw,
                            const float* __restrict__ pb, float* __restrict__ out)
{
    int b = blockIdx.x * blockDim.x + threadIdx.x;
    if (b >= 256) return;
    float s = pb[0];
#pragma unroll 4
    for (int e = 0; e < 180; ++e) s = fmaf(x[b * 180 + e], pw[e], s);
    out[b] = s;
}

static inline void launch_gemm(const float* A, int lda, const float* W, int ldw, int woff,
                               const float* bias, float* C, int M, int N, int K, int act,
                               hipStream_t s)
{
    dim3 g((M + BM - 1) / BM, (N + BN - 1) / BN), b(256);
    gemm_nt<<<g, b, 0, s>>>(A, lda, W, ldw, woff, bias, C, M, N, K, act);
}

extern "C" void kernel_launch(void* const* d_in, const int* in_sizes, int n_in,
                              void* d_out, int out_size, void* d_ws, size_t ws_size,
                              hipStream_t stream)
{
    const float* ast    = (const float*)d_in[0];   // 256x64x1024
    const float* ce_w0  = (const float*)d_in[1];   // 600x1024
    const float* ce_b0  = (const float*)d_in[2];
    const float* ce_w1  = (const float*)d_in[3];   // 350x600
    const float* ce_b1  = (const float*)d_in[4];
    const float* ce_w2  = (const float*)d_in[5];   // 200x350
    const float* ce_b2  = (const float*)d_in[6];
    const float* ce_w3  = (const float*)d_in[7];   // 180x200
    const float* ce_b3  = (const float*)d_in[8];
    const float* cc_w0  = (const float*)d_in[9];   // 200x360
    const float* cc_b0  = (const float*)d_in[10];
    const float* cc_w1  = (const float*)d_in[11];  // 180x200
    const float* cc_b1  = (const float*)d_in[12];
    const float* rg_w0  = (const float*)d_in[13];  // 200x180
    const float* rg_b0  = (const float*)d_in[14];
    const float* rg_w1  = (const float*)d_in[15];  // 180x200
    const float* rg_b1  = (const float*)d_in[16];
    const float* pred_w = (const float*)d_in[17];  // 1x180
    const float* pred_b = (const float*)d_in[18];
    const float* cl_Wih = (const float*)d_in[19];  // 720x180
    const float* cl_Whh = (const float*)d_in[20];
    const float* cl_bih = (const float*)d_in[21];
    const float* cl_bhh = (const float*)d_in[22];
    const float* nl_Wih = (const float*)d_in[23];
    const float* nl_Whh = (const float*)d_in[24];
    const float* nl_bih = (const float*)d_in[25];
    const float* nl_bhh = (const float*)d_in[26];
    const float* no_comps = (const float*)d_in[27]; // 1x180
    const float* no_nodes = (const float*)d_in[28]; // 1x180
    float* out = (float*)d_out;                     // 256 f32

    float* ws = (float*)d_ws;
    // big aliased buffers (floats):
    float* buf0  = ws;                 // 9,830,400  : act0(16384x600) -> XW_leaf(12288x720)
    float* buf1  = ws + 9830400;       // 5,734,400  : act1(16384x350) -> small buffers
    float* buf2  = ws + 15564800;      // 3,276,800  : act2(16384x200) -> Xg_leaf(12288x180)
    float* embed = ws + 18841600;      // 2,949,120  : 16384x180
    float* biases = ws + 21790720;     // 1,840
    // total ws use: 21,792,560 floats = 87.2 MB

    float* clb = biases;         // 720
    float* nlb = biases + 720;   // 720
    float* b1  = biases + 1440;  // 200
    float* b2  = biases + 1640;  // 200

    // small buffers live inside buf1 (act1 is dead once layer-2 GEMM has run)
    float* h_l        = buf1;                 // 1536x180
    float* c_l        = buf1 + 276480;        // 1536x180
    float* G          = buf1 + 552960;        // 1536x720 (shared by all step GEMMs)
    float* leaf_state = buf1 + 1658880;       // 1536x180
    float* Xg2        = buf1 + 1935360;       // 1536x180
    float* XW2        = buf1 + 2211840;       // 1536x720
    float* y200       = buf1 + 3317760;       // up to 1536x200
    float* h_m        = buf1 + 3624960;       // 768x180
    float* c_m        = buf1 + 3763200;       // 768x180
    float* mid_state  = buf1 + 3901440;       // 768x180
    float* Xg3        = buf1 + 4039680;       // 768x180
    float* XW3        = buf1 + 4177920;       // 768x720
    float* h_r        = buf1 + 4730880;       // 256x180
    float* c_r        = buf1 + 4776960;       // 256x180
    float* prog       = buf1 + 4823040;       // 256x180
    float* r200       = buf1 + 4869120;       // 256x200
    float* r180       = buf1 + 4920320;       // 256x180
    float* Xg         = buf2;                 // 12288x180
    float* XWl        = buf0;                 // 12288x720

    // ---- 1. comp-embedding MLP (16384 rows) ----
    launch_gemm(ast,  1024, ce_w0, 1024, 0, ce_b0, buf0,  16384, 600, 1024, 1, stream);
    launch_gemm(buf0, 600,  ce_w1, 600,  0, ce_b1, buf1,  16384, 350, 600,  1, stream);
    launch_gemm(buf1, 350,  ce_w2, 350,  0, ce_b2, buf2,  16384, 200, 350,  1, stream);
    launch_gemm(buf2, 200,  ce_w3, 200,  0, ce_b3, embed, 16384, 180, 200,  1, stream);

    // ---- folded biases ----
    bias_prep<<<(1840 + 255) / 256, 256, 0, stream>>>(
        cl_bih, cl_bhh, nl_bih, nl_bhh, cc_w0, cc_b0, no_nodes, no_comps,
        clb, nlb, b1, b2);

    // ---- 2. leaf LSTM: batch 1536, T=8 ----
    gather_leaf<<<(12288 * 180 + 255) / 256, 256, 0, stream>>>(embed, Xg);
    launch_gemm(Xg, 180, cl_Wih, 180, 0, clb, XWl, 12288, 720, 180, 0, stream);
    hipMemsetAsync(h_l, 0, 2 * 276480 * sizeof(float), stream);  // h_l and c_l
    for (int t = 0; t < 8; ++t) {
        launch_gemm(h_l, 180, cl_Whh, 180, 0, nullptr, G, 1536, 720, 180, 0, stream);
        lstm_gate<<<(1536 * 180 + 255) / 256, 256, 0, stream>>>(h_l, c_l, G, XWl, 1536, 8, t);
    }
    // leaf concat block: comps half of cc_w0 (cols 180:360), no_nodes folded in b1
    launch_gemm(h_l, 180, cc_w0, 360, 180, b1, y200, 1536, 200, 180, 1, stream);
    launch_gemm(y200, 200, cc_w1, 200, 0, cc_b1, leaf_state, 1536, 180, 200, 1, stream);

    // ---- 3. mid LSTM: batch 768, T=2 ----
    gather_mid<<<(1536 * 180 + 255) / 256, 256, 0, stream>>>(leaf_state, Xg2);
    launch_gemm(Xg2, 180, nl_Wih, 180, 0, nlb, XW2, 1536, 720, 180, 0, stream);
    hipMemsetAsync(h_m, 0, 2 * 138240 * sizeof(float), stream);  // h_m and c_m
    for (int t = 0; t < 2; ++t) {
        launch_gemm(h_m, 180, nl_Whh, 180, 0, nullptr, G, 768, 720, 180, 0, stream);
        lstm_gate<<<(768 * 180 + 255) / 256, 256, 0, stream>>>(h_m, c_m, G, XW2, 768, 2, t);
    }
    // interior concat: nodes half of cc_w0 (cols 0:180), no_comps folded in b2
    launch_gemm(h_m, 180, cc_w0, 360, 0, b2, y200, 768, 200, 180, 1, stream);
    launch_gemm(y200, 200, cc_w1, 200, 0, cc_b1, mid_state, 768, 180, 200, 1, stream);

    // ---- 4. root LSTM: batch 256, T=3 ----
    gather_root<<<(768 * 180 + 255) / 256, 256, 0, stream>>>(mid_state, Xg3);
    launch_gemm(Xg3, 180, nl_Wih, 180, 0, nlb, XW3, 768, 720, 180, 0, stream);
    hipMemsetAsync(h_r, 0, 2 * 46080 * sizeof(float), stream);   // h_r and c_r
    for (int t = 0; t < 3; ++t) {
        launch_gemm(h_r, 180, nl_Whh, 180, 0, nullptr, G, 256, 720, 180, 0, stream);
        lstm_gate<<<(256 * 180 + 255) / 256, 256, 0, stream>>>(h_r, c_r, G, XW3, 256, 3, t);
    }
    launch_gemm(h_r, 180, cc_w0, 360, 0, b2, y200, 256, 200, 180, 1, stream);
    launch_gemm(y200, 200, cc_w1, 200, 0, cc_b1, prog, 256, 180, 200, 1, stream);

    // ---- 5. regression + prediction ----
    launch_gemm(prog, 180, rg_w0, 180, 0, rg_b0, r200, 256, 200, 180, 1, stream);
    launch_gemm(r200, 200, rg_w1, 200, 0, rg_b1, r180, 256, 180, 200, 1, stream);
    pred_kernel<<<1, 256, 0, stream>>>(r180, pred_w, pred_b, out);
}

// Round 5
// 1271.646 us; speedup vs baseline: 1.4487x; 1.4487x over previous
//
#include <hip/hip_runtime.h>
#include <math.h>

// ---------------------------------------------------------------------------
// Model_Recursive_LSTM_v2 — round 5: big GEMMs -> bf16 split-precision MFMA.
//
// R4 profile: layer-0 f32 GEMM = 770us @ 26 TF (MfmaUtil 0, VALUBusy 27%,
// 1e7 LDS bank conflicts). MLP+leafXW ~= 1290us of 1842. No fp32 MFMA on
// CDNA4 -> represent f32 as hi+lo bf16 (RN), 3 MFMAs per product
// (hi*hi + hi*lo + lo*hi), f32 accumulate: ~2^-18 relative error, fits the
// 3.05e-4 absmax budget with margin.
//
//   - gemm_mfma<AF32,OUTPAIR>: 64x64 block tile, 4 waves (2x2), each wave
//     32x32 = 2x2 fragments of v_mfma_f32_16x16x32_bf16. No LDS (operands
//     L2/L3-resident; A fragments reused across <=12 col-blocks via L2).
//     Fragment maps per m89/m91/m156: A row=lane&15, k=(lane>>4)*8+j;
//     B(=W^T) col=lane&15 same k; D col=lane&15, row=(lane>>4)*4+reg.
//   - Layer0 converts f32 A in-registers (AF32=true) - no 67MB staging buf.
//   - Layers 0-3 write bf16 hi/lo pairs directly (fused bias+ELU+split).
//   - Leaf XW GEMM (12288x720x180) MFMA, f32 out for lstm_gate.
//   - K padded to 32 (zero-filled), W rows padded to 64.
//   - LSTM chain / concat / regression unchanged f32 (next round's target).
// ---------------------------------------------------------------------------

#define BM 64
#define BN 64
#define BK 16

typedef __attribute__((ext_vector_type(8))) short bf16x8;
typedef __attribute__((ext_vector_type(4))) float f32x4;
typedef unsigned short ushort_t;
typedef unsigned int uint_t;

__device__ __forceinline__ float elu1(float x) { return x > 0.f ? x : expm1f(x); }
__device__ __forceinline__ float sigm(float x) { return 1.f / (1.f + expf(-x)); }

__device__ __forceinline__ ushort_t f2bf(float f) {
    union { float f; uint_t u; } v; v.f = f;
    uint_t u = v.u;
    uint_t r = u + 0x7FFFu + ((u >> 16) & 1u);   // round-to-nearest-even
    return (ushort_t)(r >> 16);
}
__device__ __forceinline__ float bf2f(ushort_t h) {
    union { uint_t u; float f; } v; v.u = ((uint_t)h) << 16;
    return v.f;
}
__device__ __forceinline__ void split2(float x, ushort_t& hi, ushort_t& lo) {
    ushort_t h = f2bf(x);
    hi = h;
    lo = f2bf(x - bf2f(h));
}

__device__ __forceinline__ bf16x8 ld8(const ushort_t* p) { return *(const bf16x8*)p; }

__device__ __forceinline__ void load_split_f32(const float* p, bf16x8& h8, bf16x8& l8) {
    const float4* q = (const float4*)p;
    float4 a = q[0], b = q[1];
    float v[8] = {a.x, a.y, a.z, a.w, b.x, b.y, b.z, b.w};
#pragma unroll
    for (int i = 0; i < 8; ++i) {
        ushort_t h, l; split2(v[i], h, l);
        h8[i] = (short)h; l8[i] = (short)l;
    }
}

// C = act(A * W^T + bias). A: M x lda (f32 if AF32 else bf16 hi/lo pair),
// W: bf16 hi/lo pair, Np x ldw (rows padded to 64, zero-filled; ldw = Kp).
// OUTPAIR: write bf16 hi/lo planes M x ldc (cols >= N zeroed, cols >= ldc
// skipped); else write f32 M x N.
template <bool AF32, bool OUTPAIR>
__global__ __launch_bounds__(256)
void gemm_mfma(const void* __restrict__ Ap, const void* __restrict__ Alop, int lda,
               const ushort_t* __restrict__ Whi, const ushort_t* __restrict__ Wlo, int ldw,
               const float* __restrict__ bias,
               float* __restrict__ Cf, ushort_t* __restrict__ Chi, ushort_t* __restrict__ Clo,
               int ldc, int M, int N, int Kp, int act)
{
    const int lane = threadIdx.x & 63;
    const int wave = threadIdx.x >> 6;
    const int wm = wave & 1, wn = wave >> 1;          // 2x2 waves -> 64x64 tile
    const int r16 = lane & 15;
    const int kb  = (lane >> 4) << 3;                 // k base: 0,8,16,24
    const int bm = blockIdx.x * 64 + wm * 32;
    const int bn = blockIdx.y * 64 + wn * 32;

    f32x4 acc[2][2] = {};

    const int ar0 = (bm + r16) * lda + kb;            // A row strips
    const int ar1 = ar0 + 16 * lda;
    const ushort_t* pw0h = Whi + (bn + r16) * ldw + kb;
    const ushort_t* pw0l = Wlo + (bn + r16) * ldw + kb;
    const ushort_t* pw1h = pw0h + 16 * ldw;
    const ushort_t* pw1l = pw0l + 16 * ldw;

    for (int k = 0; k < Kp; k += 32) {
        bf16x8 a0h, a0l, a1h, a1l;
        if constexpr (AF32) {
            const float* A = (const float*)Ap;
            load_split_f32(A + ar0 + k, a0h, a0l);
            load_split_f32(A + ar1 + k, a1h, a1l);
        } else {
            const ushort_t* Ah = (const ushort_t*)Ap;
            const ushort_t* Al = (const ushort_t*)Alop;
            a0h = ld8(Ah + ar0 + k); a0l = ld8(Al + ar0 + k);
            a1h = ld8(Ah + ar1 + k); a1l = ld8(Al + ar1 + k);
        }
        bf16x8 w0h = ld8(pw0h + k), w0l = ld8(pw0l + k);
        bf16x8 w1h = ld8(pw1h + k), w1l = ld8(pw1l + k);

        acc[0][0] = __builtin_amdgcn_mfma_f32_16x16x32_bf16(a0h, w0h, acc[0][0], 0, 0, 0);
        acc[0][1] = __builtin_amdgcn_mfma_f32_16x16x32_bf16(a0h, w1h, acc[0][1], 0, 0, 0);
        acc[1][0] = __builtin_amdgcn_mfma_f32_16x16x32_bf16(a1h, w0h, acc[1][0], 0, 0, 0);
        acc[1][1] = __builtin_amdgcn_mfma_f32_16x16x32_bf16(a1h, w1h, acc[1][1], 0, 0, 0);

        acc[0][0] = __builtin_amdgcn_mfma_f32_16x16x32_bf16(a0h, w0l, acc[0][0], 0, 0, 0);
        acc[0][1] = __builtin_amdgcn_mfma_f32_16x16x32_bf16(a0h, w1l, acc[0][1], 0, 0, 0);
        acc[1][0] = __builtin_amdgcn_mfma_f32_16x16x32_bf16(a1h, w0l, acc[1][0], 0, 0, 0);
        acc[1][1] = __builtin_amdgcn_mfma_f32_16x16x32_bf16(a1h, w1l, acc[1][1], 0, 0, 0);

        acc[0][0] = __builtin_amdgcn_mfma_f32_16x16x32_bf16(a0l, w0h, acc[0][0], 0, 0, 0);
        acc[0][1] = __builtin_amdgcn_mfma_f32_16x16x32_bf16(a0l, w1h, acc[0][1], 0, 0, 0);
        acc[1][0] = __builtin_amdgcn_mfma_f32_16x16x32_bf16(a1l, w0h, acc[1][0], 0, 0, 0);
        acc[1][1] = __builtin_amdgcn_mfma_f32_16x16x32_bf16(a1l, w1h, acc[1][1], 0, 0, 0);
    }

    const int rbase = (lane >> 4) << 2;               // D row base: 0,4,8,12
#pragma unroll
    for (int ms = 0; ms < 2; ++ms)
#pragma unroll
    for (int ns = 0; ns < 2; ++ns) {
        const int gc = bn + ns * 16 + r16;
#pragma unroll
        for (int r = 0; r < 4; ++r) {
            const int gr = bm + ms * 16 + rbase + r;
            float v = acc[ms][ns][r];
            if constexpr (OUTPAIR) {
                if (gc < ldc) {
                    float o = 0.f;
                    if (gc < N) {
                        o = v + bias[gc];
                        if (act) o = elu1(o);
                    }
                    ushort_t h, l; split2(o, h, l);
                    Chi[gr * ldc + gc] = h;
                    Clo[gr * ldc + gc] = l;
                }
            } else {
                if (gc < N) {
                    float o = v + bias[gc];
                    if (act) o = elu1(o);
                    Cf[gr * N + gc] = o;
                }
            }
        }
    }
}

// f32 weight [R x C] -> bf16 hi/lo planes [Rp x Cp], zero-padded.
__global__ void conv_w(const float* __restrict__ src, ushort_t* __restrict__ dhi,
                       ushort_t* __restrict__ dlo, int R, int C, int Rp, int Cp)
{
    int idx = blockIdx.x * blockDim.x + threadIdx.x;
    if (idx >= Rp * Cp) return;
    int r = idx / Cp, c = idx - r * Cp;
    float v = (r < R && c < C) ? src[r * C + c] : 0.f;
    ushort_t h, l; split2(v, h, l);
    dhi[idx] = h; dlo[idx] = l;
}

// ------------------- f32 tail kernels (unchanged from R4) -------------------

__global__ __launch_bounds__(256)
void gemm_nt(const float* __restrict__ A, int lda,
             const float* __restrict__ W, int ldw, int woff,
             const float* __restrict__ bias,
             float* __restrict__ C, int M, int N, int K, int act)
{
    __shared__ float As[BK][BM + 4];
    __shared__ float Ws[BK][BN + 4];
    const int tid = threadIdx.x;
    const int bm = blockIdx.x * BM;
    const int bn = blockIdx.y * BN;
    const int lr = tid >> 2;
    const int lk = (tid & 3) << 2;
    const int r0 = (tid >> 4) << 2;
    const int c0 = (tid & 15) << 2;
    float acc[4][4] = {};

    for (int k0 = 0; k0 < K; k0 += BK) {
        const int arow = bm + lr;
        const int wrow = bn + lr;
#pragma unroll
        for (int u = 0; u < 4; ++u) {
            const int k = k0 + lk + u;
            As[lk + u][lr] = (arow < M && k < K) ? A[arow * lda + k] : 0.f;
            Ws[lk + u][lr] = (wrow < N && k < K) ? W[wrow * ldw + woff + k] : 0.f;
        }
        __syncthreads();
#pragma unroll
        for (int kk = 0; kk < BK; ++kk) {
            float a[4], b[4];
#pragma unroll
            for (int i = 0; i < 4; ++i) a[i] = As[kk][r0 + i];
#pragma unroll
            for (int j = 0; j < 4; ++j) b[j] = Ws[kk][c0 + j];
#pragma unroll
            for (int i = 0; i < 4; ++i)
#pragma unroll
                for (int j = 0; j < 4; ++j)
                    acc[i][j] = fmaf(a[i], b[j], acc[i][j]);
        }
        __syncthreads();
    }
#pragma unroll
    for (int i = 0; i < 4; ++i) {
        const int row = bm + r0 + i;
        if (row >= M) continue;
#pragma unroll
        for (int j = 0; j < 4; ++j) {
            const int col = bn + c0 + j;
            if (col >= N) continue;
            float v = acc[i][j];
            if (bias) v += bias[col];
            if (act) v = elu1(v);
            C[row * N + col] = v;
        }
    }
}

__global__ void lstm_gate(float* __restrict__ h, float* __restrict__ c,
                          const float* __restrict__ G, const float* __restrict__ XW,
                          int rows, int T, int t)
{
    int idx = blockIdx.x * blockDim.x + threadIdx.x;
    if (idx >= rows * 180) return;
    int n = idx / 180, e = idx - n * 180;
    const float* g  = G  + n * 720;
    const float* xw = XW + (n * T + t) * 720;
    float gi = g[e]       + xw[e];
    float gf = g[e + 180] + xw[e + 180];
    float gg = g[e + 360] + xw[e + 360];
    float go = g[e + 540] + xw[e + 540];
    float cv = sigm(gf) * c[idx] + sigm(gi) * tanhf(gg);
    c[idx] = cv;
    h[idx] = sigm(go) * tanhf(cv);
}

// leaf inputs (bf16 pair): row r = (j*256+b)*8 + t  <-  embed row b*64+8j+t
__global__ void gather_leaf_bf(const ushort_t* __restrict__ ehi, const ushort_t* __restrict__ elo,
                               ushort_t* __restrict__ xhi, ushort_t* __restrict__ xlo)
{
    int idx = blockIdx.x * blockDim.x + threadIdx.x;
    if (idx >= 12288 * 192) return;
    int r = idx / 192, e = idx - r * 192;
    int t = r & 7, nb = r >> 3;
    int b = nb & 255, j = nb >> 8;
    int s = (b * 64 + 8 * j + t) * 192 + e;
    xhi[idx] = ehi[s];
    xlo[idx] = elo[s];
}

// mid inputs: row r = (i*256+b)*2 + t  <-  leaf_state row (2i+t)*256 + b
__global__ void gather_mid(const float* __restrict__ ls, float* __restrict__ Xg)
{
    int idx = blockIdx.x * blockDim.x + threadIdx.x;
    if (idx >= 1536 * 180) return;
    int r = idx / 180, e = idx - r * 180;
    int t = r & 1, m = r >> 1;
    int b = m & 255, i = m >> 8;
    Xg[idx] = ls[((2 * i + t) * 256 + b) * 180 + e];
}

// root inputs: row r = b*3 + t  <-  mid_state row t*256 + b
__global__ void gather_root(const float* __restrict__ ms, float* __restrict__ Xg)
{
    int idx = blockIdx.x * blockDim.x + threadIdx.x;
    if (idx >= 768 * 180) return;
    int r = idx / 180, e = idx - r * 180;
    int b = r / 3, t = r - b * 3;
    Xg[idx] = ms[(t * 256 + b) * 180 + e];
}

__global__ void bias_prep(const float* __restrict__ cl_bih, const float* __restrict__ cl_bhh,
                          const float* __restrict__ nl_bih, const float* __restrict__ nl_bhh,
                          const float* __restrict__ cc_w0, const float* __restrict__ cc_b0,
                          const float* __restrict__ no_nodes, const float* __restrict__ no_comps,
                          float* __restrict__ clb, float* __restrict__ nlb,
                          float* __restrict__ b1, float* __restrict__ b2)
{
    int tid = blockIdx.x * blockDim.x + threadIdx.x;
    if (tid < 720) {
        clb[tid] = cl_bih[tid] + cl_bhh[tid];
    } else if (tid < 1440) {
        int o = tid - 720;
        nlb[o] = nl_bih[o] + nl_bhh[o];
    } else if (tid < 1640) {
        int o = tid - 1440;
        float s = cc_b0[o];
        for (int e = 0; e < 180; ++e) s = fmaf(no_nodes[e], cc_w0[o * 360 + e], s);
        b1[o] = s;
    } else if (tid < 1840) {
        int o = tid - 1640;
        float s = cc_b0[o];
        for (int e = 0; e < 180; ++e) s = fmaf(no_comps[e], cc_w0[o * 360 + 180 + e], s);
        b2[o] = s;
    }
}

__global__ void pred_kernel(const float* __restrict__ x, const float* __restrict__ pw,
                            const float* __restrict__ pb, float* __restrict__ out)
{
    int b = blockIdx.x * blockDim.x + threadIdx.x;
    if (b >= 256) return;
    float s = pb[0];
#pragma unroll 4
    for (int e = 0; e < 180; ++e) s = fmaf(x[b * 180 + e], pw[e], s);
    out[b] = s;
}

static inline void launch_gemm(const float* A, int lda, const float* W, int ldw, int woff,
                               const float* bias, float* C, int M, int N, int K, int act,
                               hipStream_t s)
{
    dim3 g((M + BM - 1) / BM, (N + BN - 1) / BN), b(256);
    gemm_nt<<<g, b, 0, s>>>(A, lda, W, ldw, woff, bias, C, M, N, K, act);
}

extern "C" void kernel_launch(void* const* d_in, const int* in_sizes, int n_in,
                              void* d_out, int out_size, void* d_ws, size_t ws_size,
                              hipStream_t stream)
{
    const float* ast    = (const float*)d_in[0];   // 256x64x1024
    const float* ce_w0  = (const float*)d_in[1];   // 600x1024
    const float* ce_b0  = (const float*)d_in[2];
    const float* ce_w1  = (const float*)d_in[3];   // 350x600
    const float* ce_b1  = (const float*)d_in[4];
    const float* ce_w2  = (const float*)d_in[5];   // 200x350
    const float* ce_b2  = (const float*)d_in[6];
    const float* ce_w3  = (const float*)d_in[7];   // 180x200
    const float* ce_b3  = (const float*)d_in[8];
    const float* cc_w0  = (const float*)d_in[9];   // 200x360
    const float* cc_b0  = (const float*)d_in[10];
    const float* cc_w1  = (const float*)d_in[11];  // 180x200
    const float* cc_b1  = (const float*)d_in[12];
    const float* rg_w0  = (const float*)d_in[13];  // 200x180
    const float* rg_b0  = (const float*)d_in[14];
    const float* rg_w1  = (const float*)d_in[15];  // 180x200
    const float* rg_b1  = (const float*)d_in[16];
    const float* pred_w = (const float*)d_in[17];  // 1x180
    const float* pred_b = (const float*)d_in[18];
    const float* cl_Wih = (const float*)d_in[19];  // 720x180
    const float* cl_Whh = (const float*)d_in[20];
    const float* cl_bih = (const float*)d_in[21];
    const float* cl_bhh = (const float*)d_in[22];
    const float* nl_Wih = (const float*)d_in[23];
    const float* nl_Whh = (const float*)d_in[24];
    const float* nl_bih = (const float*)d_in[25];
    const float* nl_bhh = (const float*)d_in[26];
    const float* no_comps = (const float*)d_in[27]; // 1x180
    const float* no_nodes = (const float*)d_in[28]; // 1x180
    float* out = (float*)d_out;                     // 256 f32

    char* ws = (char*)d_ws;

    // ---- workspace layout (bytes; total ~79.9 MB, <= proven 87 MB) ----
    // R0 (35,389,440 B): A2 pair -> embed pair -> XWl f32
    // R1 (39,845,888 B): A1 pair -> A3 pair -> {Xg pair | smalls f32}
    char* R0 = ws;
    char* R1 = ws + 35389440;
    char* WT = ws + 75235328;   // converted weights, 4,677,632 B
    char* BI = ws + 79912960;   // folded biases, 7,360 B

    // R0 tenants
    ushort_t* A2hi = (ushort_t*)R0;                         // 16384x352
    ushort_t* A2lo = (ushort_t*)(R0 + 11534336);
    ushort_t* EMhi = (ushort_t*)R0;                         // embed 16384x192
    ushort_t* EMlo = (ushort_t*)(R0 + 6291456);
    float*    XWl  = (float*)R0;                            // 12288x720 f32

    // R1 tenants
    ushort_t* A1hi = (ushort_t*)R1;                         // 16384x608
    ushort_t* A1lo = (ushort_t*)(R1 + 19922944);
    ushort_t* A3hi = (ushort_t*)R1;                         // 16384x224
    ushort_t* A3lo = (ushort_t*)(R1 + 7340032);
    ushort_t* XGhi = (ushort_t*)R1;                         // Xg 12288x192
    ushort_t* XGlo = (ushort_t*)(R1 + 4718592);
    float*    S    = (float*)(R1 + 9437184);                // smalls, 4,966,400 f32

    float* h_l        = S;
    float* c_l        = S + 276480;
    float* G          = S + 552960;      // 1536x720
    float* leaf_state = S + 1658880;
    float* Xg2        = S + 1935360;
    float* XW2        = S + 2211840;     // 1536x720
    float* y200       = S + 3317760;
    float* h_m        = S + 3624960;
    float* c_m        = S + 3763200;
    float* mid_state  = S + 3901440;
    float* Xg3        = S + 4039680;
    float* XW3        = S + 4177920;     // 768x720
    float* h_r        = S + 4730880;
    float* c_r        = S + 4776960;
    float* prog       = S + 4823040;
    float* r200       = S + 4869120;
    float* r180       = S + 4920320;

    // WT tenants (each plane zero-padded: rows->64-mult, cols->32-mult)
    ushort_t* w0hi = (ushort_t*)WT;                      // 640x1024
    ushort_t* w0lo = (ushort_t*)(WT + 1310720);
    ushort_t* w1hi = (ushort_t*)(WT + 2621440);          // 384x608
    ushort_t* w1lo = (ushort_t*)(WT + 3088384);
    ushort_t* w2hi = (ushort_t*)(WT + 3555328);          // 256x352
    ushort_t* w2lo = (ushort_t*)(WT + 3735552);
    ushort_t* w3hi = (ushort_t*)(WT + 3915776);          // 192x224
    ushort_t* w3lo = (ushort_t*)(WT + 4001792);
    ushort_t* wihhi = (ushort_t*)(WT + 4087808);         // 768x192
    ushort_t* wihlo = (ushort_t*)(WT + 4382720);

    float* clb = (float*)BI;
    float* nlb = (float*)(BI + 2880);
    float* b1  = (float*)(BI + 5760);
    float* b2  = (float*)(BI + 6560);

    // ---- 0. weight conversion + folded biases ----
    conv_w<<<(640 * 1024 + 255) / 256, 256, 0, stream>>>(ce_w0, w0hi, w0lo, 600, 1024, 640, 1024);
    conv_w<<<(384 * 608 + 255) / 256, 256, 0, stream>>>(ce_w1, w1hi, w1lo, 350, 600, 384, 608);
    conv_w<<<(256 * 352 + 255) / 256, 256, 0, stream>>>(ce_w2, w2hi, w2lo, 200, 350, 256, 352);
    conv_w<<<(192 * 224 + 255) / 256, 256, 0, stream>>>(ce_w3, w3hi, w3lo, 180, 200, 192, 224);
    conv_w<<<(768 * 192 + 255) / 256, 256, 0, stream>>>(cl_Wih, wihhi, wihlo, 720, 180, 768, 192);
    bias_prep<<<(1840 + 255) / 256, 256, 0, stream>>>(
        cl_bih, cl_bhh, nl_bih, nl_bhh, cc_w0, cc_b0, no_nodes, no_comps,
        clb, nlb, b1, b2);

    // ---- 1. comp-embedding MLP via MFMA (fused ELU + bf16-pair epilogue) ----
    {
        dim3 b(256);
        dim3 g0(256, 10); // M=16384, Np=640
        gemm_mfma<true, true><<<g0, b, 0, stream>>>(
            ast, nullptr, 1024, w0hi, w0lo, 1024, ce_b0,
            nullptr, A1hi, A1lo, 608, 16384, 600, 1024, 1);
        dim3 g1(256, 6);  // Np=384
        gemm_mfma<false, true><<<g1, b, 0, stream>>>(
            A1hi, A1lo, 608, w1hi, w1lo, 608, ce_b1,
            nullptr, A2hi, A2lo, 352, 16384, 350, 608, 1);
        dim3 g2(256, 4);  // Np=256
        gemm_mfma<false, true><<<g2, b, 0, stream>>>(
            A2hi, A2lo, 352, w2hi, w2lo, 352, ce_b2,
            nullptr, A3hi, A3lo, 224, 16384, 200, 352, 1);
        dim3 g3(256, 3);  // Np=192
        gemm_mfma<false, true><<<g3, b, 0, stream>>>(
            A3hi, A3lo, 224, w3hi, w3lo, 224, ce_b3,
            nullptr, EMhi, EMlo, 192, 16384, 180, 224, 1);
    }

    // ---- 2. leaf LSTM: batch 1536 (6 leaves x 256), T=8 ----
    gather_leaf_bf<<<(12288 * 192 + 255) / 256, 256, 0, stream>>>(EMhi, EMlo, XGhi, XGlo);
    {
        dim3 b(256), g(192, 12); // M=12288, Np=768
        gemm_mfma<false, false><<<g, b, 0, stream>>>(
            XGhi, XGlo, 192, wihhi, wihlo, 192, clb,
            XWl, nullptr, nullptr, 0, 12288, 720, 192, 0);
    }
    hipMemsetAsync(h_l, 0, 2 * 276480 * sizeof(float), stream);  // h_l and c_l
    for (int t = 0; t < 8; ++t) {
        launch_gemm(h_l, 180, cl_Whh, 180, 0, nullptr, G, 1536, 720, 180, 0, stream);
        lstm_gate<<<(1536 * 180 + 255) / 256, 256, 0, stream>>>(h_l, c_l, G, XWl, 1536, 8, t);
    }
    // leaf concat: comps half of cc_w0 (cols 180:360), no_nodes folded in b1
    launch_gemm(h_l, 180, cc_w0, 360, 180, b1, y200, 1536, 200, 180, 1, stream);
    launch_gemm(y200, 200, cc_w1, 200, 0, cc_b1, leaf_state, 1536, 180, 200, 1, stream);

    // ---- 3. mid LSTM: batch 768 (3 mids x 256), T=2 ----
    gather_mid<<<(1536 * 180 + 255) / 256, 256, 0, stream>>>(leaf_state, Xg2);
    launch_gemm(Xg2, 180, nl_Wih, 180, 0, nlb, XW2, 1536, 720, 180, 0, stream);
    hipMemsetAsync(h_m, 0, 2 * 138240 * sizeof(float), stream);
    for (int t = 0; t < 2; ++t) {
        launch_gemm(h_m, 180, nl_Whh, 180, 0, nullptr, G, 768, 720, 180, 0, stream);
        lstm_gate<<<(768 * 180 + 255) / 256, 256, 0, stream>>>(h_m, c_m, G, XW2, 768, 2, t);
    }
    // interior concat: nodes half of cc_w0 (cols 0:180), no_comps folded in b2
    launch_gemm(h_m, 180, cc_w0, 360, 0, b2, y200, 768, 200, 180, 1, stream);
    launch_gemm(y200, 200, cc_w1, 200, 0, cc_b1, mid_state, 768, 180, 200, 1, stream);

    // ---- 4. root LSTM: batch 256, T=3 ----
    gather_root<<<(768 * 180 + 255) / 256, 256, 0, stream>>>(mid_state, Xg3);
    launch_gemm(Xg3, 180, nl_Wih, 180, 0, nlb, XW3, 768, 720, 180, 0, stream);
    hipMemsetAsync(h_r, 0, 2 * 46080 * sizeof(float), stream);
    for (int t = 0; t < 3; ++t) {
        launch_gemm(h_r, 180, nl_Whh, 180, 0, nullptr, G, 256, 720, 180, 0, stream);
        lstm_gate<<<(256 * 180 + 255) / 256, 256, 0, stream>>>(h_r, c_r, G, XW3, 256, 3, t);
    }
    launch_gemm(h_r, 180, cc_w0, 360, 0, b2, y200, 256, 200, 180, 1, stream);
    launch_gemm(y200, 200, cc_w1, 200, 0, cc_b1, prog, 256, 180, 200, 1, stream);

    // ---- 5. regression + prediction ----
    launch_gemm(prog, 180, rg_w0, 180, 0, rg_b0, r200, 256, 200, 180, 1, stream);
    launch_gemm(r200, 200, rg_w1, 200, 0, rg_b1, r180, 256, 180, 200, 1, stream);
    pred_kernel<<<1, 256, 0, stream>>>(r180, pred_w, pred_b, out);
}